// Round 1
// baseline (1372.787 us; speedup 1.0000x reference)
//
#include <hip/hip_runtime.h>

// GCN 2-layer forward on MI355X.
// out[v] = log_softmax( conv2( relu( conv1(x) ) ) )
// conv(x,W,b)[v] = dinv[v] * ( sum_{edges (u,v)} g[u] + g[v] ) + b,  g[u] = dinv[u]*(x[u]@W)
// where dinv = rsqrt(deg), deg counted on col with self-loops.

#define IN_DIM 512
#define HID    64
#define OUTD   32

__device__ __forceinline__ int eidx(const int* idx32, long long e, int is64) {
    if (is64) {
        const long long* p = (const long long*)idx32;
        return (int)p[e];
    }
    return idx32[e];
}

// --- int64-vs-int32 edge_index detection ------------------------------------
// If the harness materialized int64 (little-endian, values < 2^31), the int32
// view is [v0,0,v1,0,...]; four zero high-words at odd slots => int64.
__global__ void k_detect(const int* __restrict__ idx, int* __restrict__ flag) {
    if (blockIdx.x == 0 && threadIdx.x == 0) {
        int z = (idx[1] == 0) & (idx[3] == 0) & (idx[5] == 0) & (idx[7] == 0);
        *flag = z;
    }
}

// --- degree (self-loop => init 1.0) -----------------------------------------
__global__ void k_deg_init(float* __restrict__ deg, int N) {
    int i = blockIdx.x * blockDim.x + threadIdx.x;
    if (i < N) deg[i] = 1.0f;
}

__global__ void k_deg_count(const int* __restrict__ idx, const int* __restrict__ flag,
                            float* __restrict__ deg, int E) {
    int e = blockIdx.x * blockDim.x + threadIdx.x;
    if (e >= E) return;
    const int is64 = *flag;
    int c = eidx(idx, (long long)E + e, is64);
    atomicAdd(&deg[c], 1.0f);
}

__global__ void k_dinv(const float* __restrict__ deg, float* __restrict__ dinv, int N) {
    int i = blockIdx.x * blockDim.x + threadIdx.x;
    if (i < N) {
        float d = deg[i];
        dinv[i] = (d > 0.0f) ? rsqrtf(d) : 0.0f;
    }
}

// --- layer-1 GEMM: g1[r][j] = dinv[r] * sum_k x[r,k]*W1[k,j] ----------------
// lane = j (64 cols = 64 lanes). 8 rows per wave; x addresses are wave-uniform
// (readfirstlane on wave id) so the compiler can use scalar loads, and each
// FMA is acc += s_xval * v_w1 (one SGPR operand, legal). W1 column loads are
// 256B coalesced per wave. Dual-store epilogue initializes out1 with the
// self-loop contribution.
__launch_bounds__(256)
__global__ void k_gemm1(const float* __restrict__ x, const float* __restrict__ W1,
                        const float* __restrict__ dinv,
                        float* __restrict__ g1, float* __restrict__ out1, int N) {
    const int lane = threadIdx.x & 63;
    const int wid  = __builtin_amdgcn_readfirstlane((int)(threadIdx.x >> 6));
    const int row0 = blockIdx.x * 32 + wid * 8;
    if (row0 >= N) return;

    float acc[8] = {0.f, 0.f, 0.f, 0.f, 0.f, 0.f, 0.f, 0.f};

    for (int k0 = 0; k0 < IN_DIM; k0 += 4) {
        const float w0 = W1[(k0 + 0) * HID + lane];
        const float w1 = W1[(k0 + 1) * HID + lane];
        const float w2 = W1[(k0 + 2) * HID + lane];
        const float w3 = W1[(k0 + 3) * HID + lane];
#pragma unroll
        for (int r = 0; r < 8; ++r) {
            const int row = min(row0 + r, N - 1);   // safe clamp (N%32==0 in practice)
            const float4 xv = *(const float4*)(x + (size_t)row * IN_DIM + k0);
            acc[r] = fmaf(xv.x, w0, acc[r]);
            acc[r] = fmaf(xv.y, w1, acc[r]);
            acc[r] = fmaf(xv.z, w2, acc[r]);
            acc[r] = fmaf(xv.w, w3, acc[r]);
        }
    }
#pragma unroll
    for (int r = 0; r < 8; ++r) {
        const int row = row0 + r;
        if (row < N) {
            const float v = acc[r] * dinv[row];
            g1[(size_t)row * HID + lane]   = v;   // gather source
            out1[(size_t)row * HID + lane] = v;   // self-loop init of accumulator
        }
    }
}

// --- layer-1 scatter: out1[col][j] += g1[row][j] ----------------------------
__global__ void k_scatter1(const int* __restrict__ idx, const int* __restrict__ flag,
                           const float* __restrict__ g1, float* __restrict__ out1, int E) {
    const long long tid = (long long)blockIdx.x * blockDim.x + threadIdx.x;
    const int j = (int)(tid & 63);
    const long long e = tid >> 6;
    if (e >= E) return;
    const int is64 = *flag;
    const int r = eidx(idx, e, is64);
    const int c = eidx(idx, (long long)E + e, is64);
    atomicAdd(&out1[(size_t)c * HID + j], g1[(size_t)r * HID + j]);
}

// --- layer-2 GEMM fused with layer-1 epilogue -------------------------------
// h1[r][k] = relu(dinv[r]*out1[r][k] + b1[k]);  g2[r][j] = dinv[r]*sum_k h1*W2[k,j]
// 32 lanes per row (j = lane&31), 2 rows per wave, 8 rows per 256-block.
__global__ void k_gemm2(const float* __restrict__ out1, const float* __restrict__ W2,
                        const float* __restrict__ b1, const float* __restrict__ dinv,
                        float* __restrict__ g2, float* __restrict__ out2, int N) {
    const int row = blockIdx.x * 8 + (int)(threadIdx.x >> 5);
    const int j = threadIdx.x & 31;
    if (row >= N) return;
    const float dv = dinv[row];
    float acc = 0.f;
#pragma unroll 8
    for (int k = 0; k < HID; ++k) {
        float h = fmaf(dv, out1[(size_t)row * HID + k], b1[k]);
        h = fmaxf(h, 0.f);
        acc = fmaf(h, W2[k * OUTD + j], acc);
    }
    acc *= dv;
    g2[(size_t)row * OUTD + j]   = acc;
    out2[(size_t)row * OUTD + j] = acc;   // self-loop init
}

// --- layer-2 scatter ---------------------------------------------------------
__global__ void k_scatter2(const int* __restrict__ idx, const int* __restrict__ flag,
                           const float* __restrict__ g2, float* __restrict__ out2, int E) {
    const long long tid = (long long)blockIdx.x * blockDim.x + threadIdx.x;
    const int j = (int)(tid & 31);
    const long long e = tid >> 5;
    if (e >= E) return;
    const int is64 = *flag;
    const int r = eidx(idx, e, is64);
    const int c = eidx(idx, (long long)E + e, is64);
    atomicAdd(&out2[(size_t)c * OUTD + j], g2[(size_t)r * OUTD + j]);
}

// --- final: z = dinv*out2 + b2; log_softmax over 32 cols --------------------
__global__ void k_final(const float* __restrict__ out2, const float* __restrict__ b2,
                        const float* __restrict__ dinv, float* __restrict__ out, int N) {
    const int tid = blockIdx.x * blockDim.x + threadIdx.x;
    const int row = tid >> 5;
    const int j = tid & 31;
    if (row >= N) return;
    const float z = fmaf(dinv[row], out2[(size_t)row * OUTD + j], b2[j]);
    float m = z;
#pragma unroll
    for (int d = 16; d; d >>= 1) m = fmaxf(m, __shfl_xor(m, d, 32));
    float s = expf(z - m);
#pragma unroll
    for (int d = 16; d; d >>= 1) s += __shfl_xor(s, d, 32);
    out[(size_t)row * OUTD + j] = z - m - logf(s);
}

extern "C" void kernel_launch(void* const* d_in, const int* in_sizes, int n_in,
                              void* d_out, int out_size, void* d_ws, size_t ws_size,
                              hipStream_t stream) {
    const float* x   = (const float*)d_in[0];
    const int*   idx = (const int*)d_in[1];
    const float* W1  = (const float*)d_in[2];
    const float* b1  = (const float*)d_in[3];
    const float* W2  = (const float*)d_in[4];
    const float* b2  = (const float*)d_in[5];
    float* out = (float*)d_out;

    const int N = in_sizes[0] / IN_DIM;      // 100000
    const int E = in_sizes[1] / 2;           // 1600000 (elements, regardless of 32/64-bit)

    // workspace layout (floats)
    float* ws   = (float*)d_ws;
    float* deg  = ws;                                  // N
    float* dinv = deg  + N;                            // N
    float* g1   = dinv + N;                            // N*64
    float* out1 = g1   + (size_t)N * HID;              // N*64
    float* g2   = out1 + (size_t)N * HID;              // N*32
    float* out2 = g2   + (size_t)N * OUTD;             // N*32
    int*   flag = (int*)(out2 + (size_t)N * OUTD);     // 1

    const int B = 256;

    k_detect<<<1, 64, 0, stream>>>(idx, flag);
    k_deg_init<<<(N + B - 1) / B, B, 0, stream>>>(deg, N);
    k_deg_count<<<(E + B - 1) / B, B, 0, stream>>>(idx, flag, deg, E);
    k_dinv<<<(N + B - 1) / B, B, 0, stream>>>(deg, dinv, N);

    k_gemm1<<<(N + 31) / 32, B, 0, stream>>>(x, W1, dinv, g1, out1, N);

    {
        long long total = (long long)E * HID;
        int blocks = (int)((total + B - 1) / B);
        k_scatter1<<<blocks, B, 0, stream>>>(idx, flag, g1, out1, E);
    }

    k_gemm2<<<(N + 7) / 8, B, 0, stream>>>(out1, W2, b1, dinv, g2, out2, N);

    {
        long long total = (long long)E * OUTD;
        int blocks = (int)((total + B - 1) / B);
        k_scatter2<<<blocks, B, 0, stream>>>(idx, flag, g2, out2, E);
    }

    k_final<<<(N * 32 + B - 1) / B, B, 0, stream>>>(out2, b2, dinv, out, N);
}

// Round 3
// 704.878 us; speedup vs baseline: 1.9476x; 1.9476x over previous
//
#include <hip/hip_runtime.h>

// GCN 2-layer forward on MI355X (gfx950). fp32 VALU GEMMs + CSR-based
// segmented-gather aggregation (no float atomics).
// conv(x,W,b)[v] = dinv[v]*( sum_{(u,v)} g[u] + g[v] ) + b,  g[u]=dinv[u]*(x[u]@W)

#define IN_DIM 512
#define HID    64
#define OUTD   32

__device__ __forceinline__ int eidx(const int* idx32, long long e, int is64) {
    if (is64) { const long long* p = (const long long*)idx32; return (int)p[e]; }
    return idx32[e];
}

// --- int64-vs-int32 edge_index detection ------------------------------------
__global__ void k_detect(const int* __restrict__ idx, int* __restrict__ flag) {
    if (blockIdx.x == 0 && threadIdx.x == 0) {
        int z = (idx[1] == 0) & (idx[3] == 0) & (idx[5] == 0) & (idx[7] == 0);
        *flag = z;
    }
}

__global__ void k_zero(int* __restrict__ cnt, int N) {
    int i = blockIdx.x * blockDim.x + threadIdx.x;
    if (i < N) cnt[i] = 0;
}

__global__ void k_count(const int* __restrict__ idx, const int* __restrict__ flag,
                        int* __restrict__ cnt, int E) {
    int e = blockIdx.x * blockDim.x + threadIdx.x;
    if (e >= E) return;
    const int is64 = *flag;
    int c = eidx(idx, (long long)E + e, is64);
    atomicAdd(&cnt[c], 1);
}

// --- 3-kernel exclusive scan of cnt[N] into rowptr --------------------------
__global__ void k_scanA(const int* __restrict__ cnt, int* __restrict__ rowptr,
                        int* __restrict__ part, int N) {
    __shared__ int s[256];
    const int t = threadIdx.x;
    const int i = blockIdx.x * 256 + t;
    int v = (i < N) ? cnt[i] : 0;
    s[t] = v;
    __syncthreads();
#pragma unroll
    for (int off = 1; off < 256; off <<= 1) {
        int x = (t >= off) ? s[t - off] : 0;
        __syncthreads();
        s[t] += x;
        __syncthreads();
    }
    if (i < N) rowptr[i] = s[t] - v;       // block-local exclusive
    if (t == 255) part[blockIdx.x] = s[255];
}

__global__ void k_scanB(const int* __restrict__ part, int* __restrict__ partex, int nb) {
    __shared__ int s[1024];
    const int t = threadIdx.x;
    int v = (t < nb) ? part[t] : 0;
    s[t] = v;
    __syncthreads();
#pragma unroll
    for (int off = 1; off < 1024; off <<= 1) {
        int x = (t >= off) ? s[t - off] : 0;
        __syncthreads();
        s[t] += x;
        __syncthreads();
    }
    partex[t] = s[t] - v;                  // exclusive block offsets
}

__global__ void k_scanC(int* __restrict__ rowptr, const int* __restrict__ partex,
                        int N, int E) {
    const int i = blockIdx.x * blockDim.x + threadIdx.x;
    if (i < N) rowptr[i] += partex[i >> 8];
    if (i == 0) rowptr[N] = E;
}

// dinv[v] = rsqrt(1 + in-degree)   (self-loop included)
__global__ void k_dinv(const int* __restrict__ rowptr, float* __restrict__ dinv, int N) {
    int i = blockIdx.x * blockDim.x + threadIdx.x;
    if (i < N) dinv[i] = rsqrtf((float)(1 + rowptr[i + 1] - rowptr[i]));
}

// place edge sources into CSR slots; cnt counts down from degree
__global__ void k_place(const int* __restrict__ idx, const int* __restrict__ flag,
                        int* __restrict__ cnt, const int* __restrict__ rowptr,
                        int* __restrict__ src, int E) {
    int e = blockIdx.x * blockDim.x + threadIdx.x;
    if (e >= E) return;
    const int is64 = *flag;
    int r = eidx(idx, e, is64);
    int c = eidx(idx, (long long)E + e, is64);
    int ofs = atomicAdd(&cnt[c], -1) - 1;   // unique in [0, deg)
    src[rowptr[c] + ofs] = r;
}

// --- layer-1 GEMM: g1[r][j] = dinv[r]*(x[r]@W1)[j] --------------------------
// 128 rows x 64 cols per block; 8x4 microtile per thread; K-chunks of 16.
__launch_bounds__(256)
__global__ void k_gemm1_tile(const float* __restrict__ x, const float* __restrict__ W1,
                             const float* __restrict__ dinv, float* __restrict__ g1, int N) {
    __shared__ float xs[16][136];   // transposed: xs[k][row], pad 128->136
    __shared__ float ws[16][68];    // ws[k][col], pad 64->68

    const int t = threadIdx.x;
    const int tc = t & 15;          // col group: cols tc*4..+3
    const int tr = t >> 4;          // row group: rows tr*8..+7
    const int row0 = blockIdx.x * 128;

    float acc[8][4];
#pragma unroll
    for (int i = 0; i < 8; ++i)
#pragma unroll
        for (int j = 0; j < 4; ++j) acc[i][j] = 0.0f;

    const int sr = t >> 1;          // staging row 0..127
    const int sk = (t & 1) * 8;     // staging k base 0 or 8

    for (int k0 = 0; k0 < IN_DIM; k0 += 16) {
        // stage x tile (transposed)
        int grow = row0 + sr;
        if (grow > N - 1) grow = N - 1;
        float4 a = *(const float4*)(x + (size_t)grow * IN_DIM + k0 + sk);
        float4 b = *(const float4*)(x + (size_t)grow * IN_DIM + k0 + sk + 4);
        xs[sk + 0][sr] = a.x; xs[sk + 1][sr] = a.y;
        xs[sk + 2][sr] = a.z; xs[sk + 3][sr] = a.w;
        xs[sk + 4][sr] = b.x; xs[sk + 5][sr] = b.y;
        xs[sk + 6][sr] = b.z; xs[sk + 7][sr] = b.w;
        // stage W tile
        {
            const int kk = t >> 4;
            const int c4 = (t & 15) * 4;
            float4 wv = *(const float4*)(W1 + (size_t)(k0 + kk) * HID + c4);
            *(float4*)&ws[kk][c4] = wv;
        }
        __syncthreads();
#pragma unroll
        for (int kk = 0; kk < 16; ++kk) {
            float4 wv = *(const float4*)&ws[kk][tc * 4];
            float4 xa = *(const float4*)&xs[kk][tr * 8];
            float4 xb = *(const float4*)&xs[kk][tr * 8 + 4];
            float xv[8], wj[4];
            *(float4*)&xv[0] = xa; *(float4*)&xv[4] = xb;
            *(float4*)&wj[0] = wv;
#pragma unroll
            for (int i = 0; i < 8; ++i)
#pragma unroll
                for (int j = 0; j < 4; ++j)
                    acc[i][j] = fmaf(xv[i], wj[j], acc[i][j]);
        }
        __syncthreads();
    }
#pragma unroll
    for (int i = 0; i < 8; ++i) {
        const int row = row0 + tr * 8 + i;
        if (row < N) {
            const float dv = dinv[row];
            float4 o;
            o.x = acc[i][0] * dv; o.y = acc[i][1] * dv;
            o.z = acc[i][2] * dv; o.w = acc[i][3] * dv;
            *(float4*)(g1 + (size_t)row * HID + tc * 4) = o;
        }
    }
}

// --- layer-1 gather: out1[v][:] = g1[v][:] + sum_{in-edges} g1[src][:] ------
__launch_bounds__(256)
__global__ void k_gather1(const int* __restrict__ rowptr, const int* __restrict__ src,
                          const float* __restrict__ g1, float* __restrict__ out1, int N) {
    const int v = blockIdx.x * 4 + (threadIdx.x >> 6);
    const int j = threadIdx.x & 63;
    if (v >= N) return;
    float acc = g1[(size_t)v * HID + j];    // self-loop
    int i = rowptr[v];
    const int end = rowptr[v + 1];
    for (; i + 1 < end; i += 2) {
        int r0 = src[i], r1 = src[i + 1];
        acc += g1[(size_t)r0 * HID + j];
        acc += g1[(size_t)r1 * HID + j];
    }
    if (i < end) acc += g1[(size_t)src[i] * HID + j];
    out1[(size_t)v * HID + j] = acc;
}

// --- layer-2 GEMM: g2[r][j] = dinv[r]*(relu(dinv[r]*out1[r]+b1)@W2)[j] ------
__global__ void k_gemm2(const float* __restrict__ out1, const float* __restrict__ W2,
                        const float* __restrict__ b1, const float* __restrict__ dinv,
                        float* __restrict__ g2, int N) {
    const int row = blockIdx.x * 8 + (int)(threadIdx.x >> 5);
    const int j = threadIdx.x & 31;
    if (row >= N) return;
    const float dv = dinv[row];
    float acc = 0.0f;
#pragma unroll 8
    for (int k = 0; k < HID; ++k) {
        float h = fmaf(dv, out1[(size_t)row * HID + k], b1[k]);
        h = fmaxf(h, 0.0f);
        acc = fmaf(h, W2[k * OUTD + j], acc);
    }
    g2[(size_t)row * OUTD + j] = acc * dv;
}

// --- layer-2 gather ----------------------------------------------------------
__launch_bounds__(256)
__global__ void k_gather2(const int* __restrict__ rowptr, const int* __restrict__ src,
                          const float* __restrict__ g2, float* __restrict__ out2, int N) {
    const int v = blockIdx.x * 8 + (threadIdx.x >> 5);
    const int j = threadIdx.x & 31;
    if (v >= N) return;
    float acc = g2[(size_t)v * OUTD + j];   // self-loop
    int i = rowptr[v];
    const int end = rowptr[v + 1];
    for (; i + 1 < end; i += 2) {
        int r0 = src[i], r1 = src[i + 1];
        acc += g2[(size_t)r0 * OUTD + j];
        acc += g2[(size_t)r1 * OUTD + j];
    }
    if (i < end) acc += g2[(size_t)src[i] * OUTD + j];
    out2[(size_t)v * OUTD + j] = acc;
}

// --- final: z = dinv*out2 + b2; log_softmax over 32 cols ---------------------
__global__ void k_final(const float* __restrict__ out2, const float* __restrict__ b2,
                        const float* __restrict__ dinv, float* __restrict__ out, int N) {
    const int tid = blockIdx.x * blockDim.x + threadIdx.x;
    const int row = tid >> 5;
    const int j = tid & 31;
    if (row >= N) return;
    const float z = fmaf(dinv[row], out2[(size_t)row * OUTD + j], b2[j]);
    float m = z;
#pragma unroll
    for (int d = 16; d; d >>= 1) m = fmaxf(m, __shfl_xor(m, d, 32));
    float s = expf(z - m);
#pragma unroll
    for (int d = 16; d; d >>= 1) s += __shfl_xor(s, d, 32);
    out[(size_t)row * OUTD + j] = z - m - logf(s);
}

extern "C" void kernel_launch(void* const* d_in, const int* in_sizes, int n_in,
                              void* d_out, int out_size, void* d_ws, size_t ws_size,
                              hipStream_t stream) {
    const float* x   = (const float*)d_in[0];
    const int*   idx = (const int*)d_in[1];
    const float* W1  = (const float*)d_in[2];
    const float* b1  = (const float*)d_in[3];
    const float* W2  = (const float*)d_in[4];
    const float* b2  = (const float*)d_in[5];
    float* out = (float*)d_out;

    const int N = in_sizes[0] / IN_DIM;      // 100000
    const int E = in_sizes[1] / 2;           // 1600000

    // ---- workspace layout (all regions 16B-aligned) ----
    int* cnt    = (int*)d_ws;                          // N
    int* rowptr = cnt + N;                             // N+4 (padded)
    int* part   = rowptr + (N + 4);                    // 1024
    int* partex = part + 1024;                         // 1024
    int* srcA   = partex + 1024;                       // E
    int* flag   = srcA + E;                            // 4 (padded)
    float* dinv = (float*)(flag + 4);                  // N
    float* g1   = dinv + N;                            // 64N (reused as out2)
    float* out1 = g1 + (size_t)N * HID;                // 64N
    float* g2   = out1 + (size_t)N * HID;              // 32N
    float* out2 = g1;                                  // alias: g1 dead after gather1

    const int B = 256;
    const int nb = (N + 255) / 256;

    k_detect<<<1, 64, 0, stream>>>(idx, flag);
    k_zero<<<(N + B - 1) / B, B, 0, stream>>>(cnt, N);
    k_count<<<(E + B - 1) / B, B, 0, stream>>>(idx, flag, cnt, E);
    k_scanA<<<nb, 256, 0, stream>>>(cnt, rowptr, part, N);
    k_scanB<<<1, 1024, 0, stream>>>(part, partex, nb);
    k_scanC<<<nb, 256, 0, stream>>>(rowptr, partex, N, E);
    k_dinv<<<(N + B - 1) / B, B, 0, stream>>>(rowptr, dinv, N);
    k_place<<<(E + B - 1) / B, B, 0, stream>>>(idx, flag, cnt, rowptr, srcA, E);

    k_gemm1_tile<<<(N + 127) / 128, 256, 0, stream>>>(x, W1, dinv, g1, N);
    k_gather1<<<(N + 3) / 4, 256, 0, stream>>>(rowptr, srcA, g1, out1, N);
    k_gemm2<<<(N + 7) / 8, B, 0, stream>>>(out1, W2, b1, dinv, g2, N);
    k_gather2<<<(N + 7) / 8, B, 0, stream>>>(rowptr, srcA, g2, out2, N);
    k_final<<<(N * 32 + B - 1) / B, B, 0, stream>>>(out2, b2, dinv, out, N);
}

// Round 4
// 644.149 us; speedup vs baseline: 2.1312x; 1.0943x over previous
//
#include <hip/hip_runtime.h>

// GCN 2-layer forward on MI355X (gfx950).
// conv(x,W,b)[v] = dinv[v]*( sum_{(u,v)} g[u] + g[v] ) + b,  g[u]=dinv[u]*(x[u]@W)
// gemm1 = MFMA bf16 3-term split (hi/lo) ~fp32 accuracy; aggregation = CSR gather
// (no float atomics); layer-2 GEMM fused into gather1; log_softmax fused into gather2.

#define IN_DIM 512
#define HID    64
#define OUTD   32

typedef __attribute__((ext_vector_type(8))) short bf16x8;
typedef __attribute__((ext_vector_type(4))) float floatx4;
typedef __attribute__((ext_vector_type(4))) unsigned short ushort4v;
typedef __attribute__((ext_vector_type(8))) unsigned short ushort8v;

__device__ __forceinline__ unsigned short f2bf(float f) {
    unsigned int u = __float_as_uint(f);
    unsigned int r = (u + 0x7fffu + ((u >> 16) & 1u)) >> 16;
    return (unsigned short)r;
}
__device__ __forceinline__ float bf2f(unsigned short h) {
    return __uint_as_float(((unsigned int)h) << 16);
}

__device__ __forceinline__ int eidx(const int* idx32, long long e, int is64) {
    if (is64) { const long long* p = (const long long*)idx32; return (int)p[e]; }
    return idx32[e];
}

// --- int64-vs-int32 edge_index detection ------------------------------------
__global__ void k_detect(const int* __restrict__ idx, int* __restrict__ flag) {
    if (blockIdx.x == 0 && threadIdx.x == 0) {
        int z = (idx[1] == 0) & (idx[3] == 0) & (idx[5] == 0) & (idx[7] == 0);
        *flag = z;
    }
}

// --- one-time W1 transpose + bf16 hi/lo split: W1t[n][k] (64 x 512) ---------
__global__ void k_prepW(const float* __restrict__ W1,
                        unsigned short* __restrict__ W1t_hi,
                        unsigned short* __restrict__ W1t_lo) {
    int t = blockIdx.x * blockDim.x + threadIdx.x;
    if (t < 64 * 512) {
        int n = t >> 9, k = t & 511;
        float v = W1[k * HID + n];
        unsigned short h = f2bf(v);
        W1t_hi[t] = h;
        W1t_lo[t] = f2bf(v - bf2f(h));
    }
}

// --- CSR build ---------------------------------------------------------------
__global__ void k_zero(int* __restrict__ cnt, int N) {
    int i = blockIdx.x * blockDim.x + threadIdx.x;
    if (i < N) cnt[i] = 0;
}

__global__ void k_count(const int* __restrict__ idx, const int* __restrict__ flag,
                        int* __restrict__ cnt, int E) {
    int e = blockIdx.x * blockDim.x + threadIdx.x;
    if (e >= E) return;
    const int is64 = *flag;
    int c = eidx(idx, (long long)E + e, is64);
    atomicAdd(&cnt[c], 1);
}

__global__ void k_scanA(const int* __restrict__ cnt, int* __restrict__ rowptr,
                        int* __restrict__ part, int N) {
    __shared__ int s[256];
    const int t = threadIdx.x;
    const int i = blockIdx.x * 256 + t;
    int v = (i < N) ? cnt[i] : 0;
    s[t] = v;
    __syncthreads();
#pragma unroll
    for (int off = 1; off < 256; off <<= 1) {
        int x = (t >= off) ? s[t - off] : 0;
        __syncthreads();
        s[t] += x;
        __syncthreads();
    }
    if (i < N) rowptr[i] = s[t] - v;
    if (t == 255) part[blockIdx.x] = s[255];
}

__global__ void k_scanB(const int* __restrict__ part, int* __restrict__ partex, int nb) {
    __shared__ int s[1024];
    const int t = threadIdx.x;
    int v = (t < nb) ? part[t] : 0;
    s[t] = v;
    __syncthreads();
#pragma unroll
    for (int off = 1; off < 1024; off <<= 1) {
        int x = (t >= off) ? s[t - off] : 0;
        __syncthreads();
        s[t] += x;
        __syncthreads();
    }
    partex[t] = s[t] - v;
}

__global__ void k_scanC(int* __restrict__ rowptr, const int* __restrict__ partex,
                        int N, int E) {
    const int i = blockIdx.x * blockDim.x + threadIdx.x;
    if (i < N) rowptr[i] += partex[i >> 8];
    if (i == 0) rowptr[N] = E;
}

__global__ void k_dinv(const int* __restrict__ rowptr, float* __restrict__ dinv, int N) {
    int i = blockIdx.x * blockDim.x + threadIdx.x;
    if (i < N) dinv[i] = rsqrtf((float)(1 + rowptr[i + 1] - rowptr[i]));
}

__global__ void k_place(const int* __restrict__ idx, const int* __restrict__ flag,
                        int* __restrict__ cnt, const int* __restrict__ rowptr,
                        int* __restrict__ src, int E) {
    int e = blockIdx.x * blockDim.x + threadIdx.x;
    if (e >= E) return;
    const int is64 = *flag;
    int r = eidx(idx, e, is64);
    int c = eidx(idx, (long long)E + e, is64);
    int ofs = atomicAdd(&cnt[c], -1) - 1;
    src[rowptr[c] + ofs] = r;
}

// --- layer-1 GEMM via MFMA: g1[r][j] = dinv[r]*(x[r]@W1)[j] ------------------
// 64-row M-tile per block (4 waves x 16 rows), 64 cols (4 n-tiles), K-chunks 64.
// bf16 hi/lo split, 3 MFMA terms: hi*hi + lo*hi + hi*lo (fp32 accumulate).
__launch_bounds__(256)
__global__ void k_gemm1_mfma(const float* __restrict__ x,
                             const unsigned short* __restrict__ Wt_hi,
                             const unsigned short* __restrict__ Wt_lo,
                             const float* __restrict__ dinv,
                             float* __restrict__ g1, int N) {
    __shared__ unsigned short xs_hi[64 * 72];
    __shared__ unsigned short xs_lo[64 * 72];
    __shared__ unsigned short ws_hi[64 * 72];
    __shared__ unsigned short ws_lo[64 * 72];

    const int t = threadIdx.x;
    const int lane = t & 63;
    const int w = t >> 6;            // wave 0..3
    const int m = lane & 15;         // A row / B col / D col
    const int quad = lane >> 4;      // k-group / D row-group
    const int row_base = blockIdx.x * 64;

    const floatx4 zero = {0.0f, 0.0f, 0.0f, 0.0f};
    floatx4 acc[4] = {zero, zero, zero, zero};

    for (int kc = 0; kc < IN_DIM; kc += 64) {
        // stage x: 64 rows x 64 k, fp32 -> bf16 hi/lo. Each thread: 4 rows x 4 k.
        {
            const int kq = (t & 15) * 4;
#pragma unroll
            for (int p = 0; p < 4; ++p) {
                int rl = (t >> 4) + p * 16;
                int row = row_base + rl;
                if (row > N - 1) row = N - 1;
                float4 v = *(const float4*)(x + (size_t)row * IN_DIM + kc + kq);
                ushort4v hi, lo;
                hi.x = f2bf(v.x); lo.x = f2bf(v.x - bf2f(hi.x));
                hi.y = f2bf(v.y); lo.y = f2bf(v.y - bf2f(hi.y));
                hi.z = f2bf(v.z); lo.z = f2bf(v.z - bf2f(hi.z));
                hi.w = f2bf(v.w); lo.w = f2bf(v.w - bf2f(hi.w));
                *(ushort4v*)&xs_hi[rl * 72 + kq] = hi;
                *(ushort4v*)&xs_lo[rl * 72 + kq] = lo;
            }
        }
        // stage W: 64 n x 64 k. Each thread: 1 n-row x 16 k (= 2 ushort8v per plane).
        // (Round-2 bug was here: ushort8v is 8 shorts; q*16 spacing left half of k unstaged.)
        {
            const int nl = t >> 2;
            const int q = (t & 3) * 16;
            const unsigned short* ph = Wt_hi + (size_t)nl * IN_DIM + kc + q;
            const unsigned short* pl = Wt_lo + (size_t)nl * IN_DIM + kc + q;
            *(ushort8v*)&ws_hi[nl * 72 + q]     = *(const ushort8v*)(ph);
            *(ushort8v*)&ws_hi[nl * 72 + q + 8] = *(const ushort8v*)(ph + 8);
            *(ushort8v*)&ws_lo[nl * 72 + q]     = *(const ushort8v*)(pl);
            *(ushort8v*)&ws_lo[nl * 72 + q + 8] = *(const ushort8v*)(pl + 8);
        }
        __syncthreads();
#pragma unroll
        for (int ks = 0; ks < 2; ++ks) {
            const int ko = ks * 32 + quad * 8;
            bf16x8 a_hi = *(const bf16x8*)&xs_hi[(w * 16 + m) * 72 + ko];
            bf16x8 a_lo = *(const bf16x8*)&xs_lo[(w * 16 + m) * 72 + ko];
#pragma unroll
            for (int nt = 0; nt < 4; ++nt) {
                bf16x8 b_hi = *(const bf16x8*)&ws_hi[(nt * 16 + m) * 72 + ko];
                bf16x8 b_lo = *(const bf16x8*)&ws_lo[(nt * 16 + m) * 72 + ko];
                acc[nt] = __builtin_amdgcn_mfma_f32_16x16x32_bf16(a_hi, b_hi, acc[nt], 0, 0, 0);
                acc[nt] = __builtin_amdgcn_mfma_f32_16x16x32_bf16(a_lo, b_hi, acc[nt], 0, 0, 0);
                acc[nt] = __builtin_amdgcn_mfma_f32_16x16x32_bf16(a_hi, b_lo, acc[nt], 0, 0, 0);
            }
        }
        __syncthreads();
    }
    // D layout: col = lane&15, row = quad*4 + r
#pragma unroll
    for (int r = 0; r < 4; ++r) {
        const int row = row_base + w * 16 + quad * 4 + r;
        if (row < N) {
            const float dv = dinv[row];
#pragma unroll
            for (int nt = 0; nt < 4; ++nt)
                g1[(size_t)row * HID + nt * 16 + m] = acc[nt][r] * dv;
        }
    }
}

// --- fused layer-1 aggregate + layer-2 GEMM ----------------------------------
// wave per node v: a1[j] = g1[v][j] + sum_in g1[src][j] (j = lane, 64 feats);
// h = relu(dinv[v]*a1 + b1); g2[v][:] = dinv[v] * (h @ W2)  (dot via LDS).
__launch_bounds__(256)
__global__ void k_agg1_gemm2(const int* __restrict__ rowptr, const int* __restrict__ src,
                             const float* __restrict__ g1, const float* __restrict__ W2,
                             const float* __restrict__ b1, const float* __restrict__ dinv,
                             float* __restrict__ g2, int N) {
    __shared__ float w2s[HID * OUTD];   // 8 KB, W2[k][j] row-major
    __shared__ float hs[4][HID];        // per-wave h row

    const int t = threadIdx.x;
    for (int i = t; i < HID * OUTD; i += 256) w2s[i] = W2[i];

    const int w = t >> 6, lane = t & 63;
    const int v = blockIdx.x * 4 + w;
    float dv = 0.0f;
    if (v < N) {
        float acc = g1[(size_t)v * HID + lane];   // self-loop
        int i = rowptr[v];
        const int end = rowptr[v + 1];
        for (; i + 1 < end; i += 2) {
            int r0 = src[i], r1 = src[i + 1];
            acc += g1[(size_t)r0 * HID + lane] + g1[(size_t)r1 * HID + lane];
        }
        if (i < end) acc += g1[(size_t)src[i] * HID + lane];
        dv = dinv[v];
        hs[w][lane] = fmaxf(fmaf(dv, acc, b1[lane]), 0.0f);
    }
    __syncthreads();   // covers w2s staging AND hs rows
    if (v < N) {
        const int j = lane & 31, half = lane >> 5;
        float s = 0.0f;
#pragma unroll
        for (int k = 0; k < 32; ++k) {
            const int kk = half * 32 + k;
            s = fmaf(hs[w][kk], w2s[kk * OUTD + j], s);
        }
        s += __shfl_down(s, 32);   // fold upper half's partial into lanes 0..31
        if (lane < 32) g2[(size_t)v * OUTD + j] = s * dv;
    }
}

// --- fused layer-2 aggregate + bias + log_softmax ----------------------------
__global__ void k_out(const int* __restrict__ rowptr, const int* __restrict__ src,
                      const float* __restrict__ g2, const float* __restrict__ b2,
                      const float* __restrict__ dinv, float* __restrict__ out, int N) {
    const int v = blockIdx.x * 8 + (int)(threadIdx.x >> 5);
    const int j = threadIdx.x & 31;
    if (v >= N) return;
    float acc = g2[(size_t)v * OUTD + j];   // self-loop
    int i = rowptr[v];
    const int end = rowptr[v + 1];
    for (; i + 1 < end; i += 2) {
        int r0 = src[i], r1 = src[i + 1];
        acc += g2[(size_t)r0 * OUTD + j] + g2[(size_t)r1 * OUTD + j];
    }
    if (i < end) acc += g2[(size_t)src[i] * OUTD + j];
    const float z = fmaf(dinv[v], acc, b2[j]);
    float m = z;
#pragma unroll
    for (int d = 16; d; d >>= 1) m = fmaxf(m, __shfl_xor(m, d, 32));
    float s = expf(z - m);
#pragma unroll
    for (int d = 16; d; d >>= 1) s += __shfl_xor(s, d, 32);
    out[(size_t)v * OUTD + j] = z - m - logf(s);
}

extern "C" void kernel_launch(void* const* d_in, const int* in_sizes, int n_in,
                              void* d_out, int out_size, void* d_ws, size_t ws_size,
                              hipStream_t stream) {
    const float* x   = (const float*)d_in[0];
    const int*   idx = (const int*)d_in[1];
    const float* W1  = (const float*)d_in[2];
    const float* b1  = (const float*)d_in[3];
    const float* W2  = (const float*)d_in[4];
    const float* b2  = (const float*)d_in[5];
    float* out = (float*)d_out;

    const int N = in_sizes[0] / IN_DIM;      // 100000
    const int E = in_sizes[1] / 2;           // 1600000

    // ---- workspace layout ----
    unsigned short* W1t_hi = (unsigned short*)d_ws;        // 64*512 shorts
    unsigned short* W1t_lo = W1t_hi + 64 * 512;
    int* cnt    = (int*)(W1t_lo + 64 * 512);               // N
    int* rowptr = cnt + N;                                 // N+4
    int* part   = rowptr + (N + 4);                        // 1024
    int* partex = part + 1024;                             // 1024
    int* srcA   = partex + 1024;                           // E
    int* flag   = srcA + E;                                // 4
    float* dinv = (float*)(flag + 4);                      // N
    float* g1   = dinv + N;                                // 64N
    float* g2   = g1 + (size_t)N * HID;                    // 32N

    const int B = 256;
    const int nb = (N + 255) / 256;

    k_detect<<<1, 64, 0, stream>>>(idx, flag);
    k_prepW<<<(64 * 512 + B - 1) / B, B, 0, stream>>>(W1, W1t_hi, W1t_lo);
    k_zero<<<(N + B - 1) / B, B, 0, stream>>>(cnt, N);
    k_count<<<(E + B - 1) / B, B, 0, stream>>>(idx, flag, cnt, E);
    k_scanA<<<nb, 256, 0, stream>>>(cnt, rowptr, part, N);
    k_scanB<<<1, 1024, 0, stream>>>(part, partex, nb);
    k_scanC<<<nb, 256, 0, stream>>>(rowptr, partex, N, E);
    k_dinv<<<(N + B - 1) / B, B, 0, stream>>>(rowptr, dinv, N);
    k_place<<<(E + B - 1) / B, B, 0, stream>>>(idx, flag, cnt, rowptr, srcA, E);

    k_gemm1_mfma<<<(N + 63) / 64, 256, 0, stream>>>(x, W1t_hi, W1t_lo, dinv, g1, N);
    k_agg1_gemm2<<<(N + 3) / 4, 256, 0, stream>>>(rowptr, srcA, g1, W2, b1, dinv, g2, N);
    k_out<<<(N + 7) / 8, B, 0, stream>>>(rowptr, srcA, g2, b2, dinv, out, N);
}